// Round 1
// baseline (164.954 us; speedup 1.0000x reference)
//
#include <hip/hip_runtime.h>
#include <math.h>

#define BB   256
#define DD   512
#define NB   314
#define NT   1024
#define NW   16   // waves per block

__device__ __forceinline__ float wred_sum(float v){
#pragma unroll
    for (int o = 32; o >= 1; o >>= 1) v += __shfl_xor(v, o, 64);
    return v;
}
__device__ __forceinline__ float wred_max(float v){
#pragma unroll
    for (int o = 32; o >= 1; o >>= 1) v = fmaxf(v, __shfl_xor(v, o, 64));
    return v;
}

__global__ __launch_bounds__(NT, 1)
void pcls_kernel(const float* __restrict__ x,
                 const float* __restrict__ lnw,
                 const float* __restrict__ lnb,
                 const float* __restrict__ w1, const float* __restrict__ b1,
                 const float* __restrict__ w2, const float* __restrict__ b2,
                 const float* __restrict__ w3, const float* __restrict__ b3,
                 const float* __restrict__ ow, const float* __restrict__ ob,
                 float* __restrict__ phi, float* __restrict__ logits)
{
    const int b    = blockIdx.x;
    const int tid  = threadIdx.x;
    const int lane = tid & 63;
    const int wid  = tid >> 6;

    __shared__ float hbuf[2][DD];
    __shared__ float redA[NW], redB[NW], redC[NW];
    __shared__ float stats[2];
    __shared__ float lsm[NB];

    // ---------- LayerNorm (biased var, eps=1e-5) ----------
    float xv = (tid < DD) ? x[(size_t)b*DD + tid] : 0.f;
    float s1 = wred_sum(xv);
    float s2 = wred_sum(xv*xv);
    if (lane == 0){ redA[wid] = s1; redB[wid] = s2; }
    __syncthreads();
    if (tid == 0){
        float a = 0.f, c = 0.f;
#pragma unroll
        for (int i = 0; i < NW; ++i){ a += redA[i]; c += redB[i]; }
        float mean = a * (1.0f/DD);
        float var  = c * (1.0f/DD) - mean*mean;
        stats[0] = mean;
        stats[1] = rsqrtf(var + 1e-5f);
    }
    __syncthreads();
    if (tid < DD){
        float hv = (xv - stats[0]) * stats[1] * lnw[(size_t)b*DD + tid]
                 + lnb[(size_t)b*DD + tid];
        hbuf[0][tid] = hv;
    }
    __syncthreads();

    // ---------- 3x (D x D matvec + bias + exact GELU) ----------
    int cur = 0;
    const float* Ws[3] = {w1, w2, w3};
    const float* Bs[3] = {b1, b2, b3};
#pragma unroll 1
    for (int L = 0; L < 3; ++L){
        const float* W  = Ws[L] + (size_t)b*DD*DD;
        const float* Bv = Bs[L] + (size_t)b*DD;
        const float4 h0 = *reinterpret_cast<const float4*>(&hbuf[cur][lane*4]);
        const float4 h1 = *reinterpret_cast<const float4*>(&hbuf[cur][256 + lane*4]);
#pragma unroll 4
        for (int r = wid; r < DD; r += NW){
            const float* wr = W + (size_t)r*DD;
            const float4 a0 = *reinterpret_cast<const float4*>(wr + lane*4);
            const float4 a1 = *reinterpret_cast<const float4*>(wr + 256 + lane*4);
            float p = a0.x*h0.x + a0.y*h0.y + a0.z*h0.z + a0.w*h0.w
                    + a1.x*h1.x + a1.y*h1.y + a1.z*h1.z + a1.w*h1.w;
            p = wred_sum(p);
            float v = p + Bv[r];                       // wave-uniform scalar load
            v = 0.5f * v * (1.0f + erff(v * 0.70710678118654752440f)); // exact GELU
            if (lane == 0) hbuf[cur^1][r] = v;
        }
        __syncthreads();
        cur ^= 1;
    }

    // ---------- out layer: NB x D matvec + bias ----------
    {
        const float* W  = ow + (size_t)b*NB*DD;
        const float* Bv = ob + (size_t)b*NB;
        const float4 h0 = *reinterpret_cast<const float4*>(&hbuf[cur][lane*4]);
        const float4 h1 = *reinterpret_cast<const float4*>(&hbuf[cur][256 + lane*4]);
#pragma unroll 2
        for (int r = wid; r < NB; r += NW){
            const float* wr = W + (size_t)r*DD;
            const float4 a0 = *reinterpret_cast<const float4*>(wr + lane*4);
            const float4 a1 = *reinterpret_cast<const float4*>(wr + 256 + lane*4);
            float p = a0.x*h0.x + a0.y*h0.y + a0.z*h0.z + a0.w*h0.w
                    + a1.x*h1.x + a1.y*h1.y + a1.z*h1.z + a1.w*h1.w;
            p = wred_sum(p);
            if (lane == 0) lsm[r] = p + Bv[r];
        }
        __syncthreads();
    }

    // ---------- softmax + circular mean -> atan2 ----------
    {
        float lv = (tid < NB) ? lsm[tid] : -INFINITY;
        float m = wred_max(lv);
        if (lane == 0) redA[wid] = m;
        __syncthreads();
        if (tid == 0){
            float mm = -INFINITY;
#pragma unroll
            for (int i = 0; i < NW; ++i) mm = fmaxf(mm, redA[i]);
            stats[0] = mm;
        }
        __syncthreads();
        const float mm = stats[0];
        float es = 0.f, ec = 0.f;
        if (tid < NB){
            float e = expf(lv - mm);
            // bin center: -pi + 2*pi*(k+0.5)/NB
            float center = -3.14159265358979323846f
                         + 6.28318530717958647692f * ((float)tid + 0.5f) * (1.0f/NB);
            es = e * sinf(center);
            ec = e * cosf(center);
        }
        float ss = wred_sum(es);
        float sc = wred_sum(ec);
        if (lane == 0){ redB[wid] = ss; redC[wid] = sc; }
        __syncthreads();
        if (tid == 0){
            float S = 0.f, C = 0.f;
#pragma unroll
            for (int i = 0; i < NW; ++i){ S += redB[i]; C += redC[i]; }
            phi[b] = atan2f(S, C);   // softmax normalizer cancels in atan2
        }
        if (tid < NB) logits[(size_t)b*NB + tid] = lv;
    }
}

extern "C" void kernel_launch(void* const* d_in, const int* in_sizes, int n_in,
                              void* d_out, int out_size, void* d_ws, size_t ws_size,
                              hipStream_t stream)
{
    const float* x   = (const float*)d_in[0];
    const float* lnw = (const float*)d_in[1];
    const float* lnb = (const float*)d_in[2];
    const float* w1  = (const float*)d_in[3];
    const float* b1  = (const float*)d_in[4];
    const float* w2  = (const float*)d_in[5];
    const float* b2  = (const float*)d_in[6];
    const float* w3  = (const float*)d_in[7];
    const float* b3  = (const float*)d_in[8];
    const float* ow  = (const float*)d_in[9];
    const float* ob  = (const float*)d_in[10];

    float* out    = (float*)d_out;
    float* phi    = out;        // [256]
    float* logits = out + BB;   // [256*314]

    pcls_kernel<<<dim3(BB), dim3(NT), 0, stream>>>(
        x, lnw, lnb, w1, b1, w2, b2, w3, b3, ow, ob, phi, logits);
}

// Round 3
// 146.249 us; speedup vs baseline: 1.1279x; 1.1279x over previous
//
#include <hip/hip_runtime.h>
#include <math.h>

#define BB   256
#define DD   512
#define NB   314
#define NT   1024
#define NW   16   // waves per block

typedef float f4v __attribute__((ext_vector_type(4)));

__device__ __forceinline__ float wred_sum(float v){
#pragma unroll
    for (int o = 32; o >= 1; o >>= 1) v += __shfl_xor(v, o, 64);
    return v;
}
__device__ __forceinline__ float wred_max(float v){
#pragma unroll
    for (int o = 32; o >= 1; o >>= 1) v = fmaxf(v, __shfl_xor(v, o, 64));
    return v;
}
// non-temporal float4 load (weights are strictly read-once per dispatch)
__device__ __forceinline__ f4v ldnt4(const float* p){
    return __builtin_nontemporal_load(reinterpret_cast<const f4v*>(p));
}

__global__ __launch_bounds__(NT, 1)
void pcls_kernel(const float* __restrict__ x,
                 const float* __restrict__ lnw,
                 const float* __restrict__ lnb,
                 const float* __restrict__ w1, const float* __restrict__ b1,
                 const float* __restrict__ w2, const float* __restrict__ b2,
                 const float* __restrict__ w3, const float* __restrict__ b3,
                 const float* __restrict__ ow, const float* __restrict__ ob,
                 float* __restrict__ phi, float* __restrict__ logits)
{
    const int b    = blockIdx.x;
    const int tid  = threadIdx.x;
    const int lane = tid & 63;
    const int wid  = tid >> 6;

    __shared__ float hbuf[2][DD];
    __shared__ float redA[NW], redB[NW], redC[NW];
    __shared__ float stats[2];
    __shared__ float lsm[NB];

    // ---------- LayerNorm (biased var, eps=1e-5) ----------
    float xv = (tid < DD) ? x[(size_t)b*DD + tid] : 0.f;
    float s1 = wred_sum(xv);
    float s2 = wred_sum(xv*xv);
    if (lane == 0){ redA[wid] = s1; redB[wid] = s2; }
    __syncthreads();
    if (tid == 0){
        float a = 0.f, c = 0.f;
#pragma unroll
        for (int i = 0; i < NW; ++i){ a += redA[i]; c += redB[i]; }
        float mean = a * (1.0f/DD);
        float var  = c * (1.0f/DD) - mean*mean;
        stats[0] = mean;
        stats[1] = rsqrtf(var + 1e-5f);
    }
    __syncthreads();
    if (tid < DD){
        float hv = (xv - stats[0]) * stats[1] * lnw[(size_t)b*DD + tid]
                 + lnb[(size_t)b*DD + tid];
        hbuf[0][tid] = hv;
    }
    __syncthreads();

    // ---------- 3x (D x D matvec + bias + exact GELU) ----------
    int cur = 0;
    const float* Ws[3] = {w1, w2, w3};
    const float* Bs[3] = {b1, b2, b3};
#pragma unroll 1
    for (int L = 0; L < 3; ++L){
        const float* W  = Ws[L] + (size_t)b*DD*DD;
        const float* Bv = Bs[L] + (size_t)b*DD;
        const float4 h0 = *reinterpret_cast<const float4*>(&hbuf[cur][lane*4]);
        const float4 h1 = *reinterpret_cast<const float4*>(&hbuf[cur][256 + lane*4]);
#pragma unroll 8
        for (int r = wid; r < DD; r += NW){
            const float* wr = W + (size_t)r*DD;
            const f4v a0 = ldnt4(wr + lane*4);
            const f4v a1 = ldnt4(wr + 256 + lane*4);
            float p = a0.x*h0.x + a0.y*h0.y + a0.z*h0.z + a0.w*h0.w
                    + a1.x*h1.x + a1.y*h1.y + a1.z*h1.z + a1.w*h1.w;
            p = wred_sum(p);
            float v = p + Bv[r];                       // wave-uniform scalar load
            v = 0.5f * v * (1.0f + erff(v * 0.70710678118654752440f)); // exact GELU
            if (lane == 0) hbuf[cur^1][r] = v;
        }
        __syncthreads();
        cur ^= 1;
    }

    // ---------- out layer: NB x D matvec + bias ----------
    {
        const float* W  = ow + (size_t)b*NB*DD;
        const float* Bv = ob + (size_t)b*NB;
        const float4 h0 = *reinterpret_cast<const float4*>(&hbuf[cur][lane*4]);
        const float4 h1 = *reinterpret_cast<const float4*>(&hbuf[cur][256 + lane*4]);
#pragma unroll 4
        for (int r = wid; r < NB; r += NW){
            const float* wr = W + (size_t)r*DD;
            const f4v a0 = ldnt4(wr + lane*4);
            const f4v a1 = ldnt4(wr + 256 + lane*4);
            float p = a0.x*h0.x + a0.y*h0.y + a0.z*h0.z + a0.w*h0.w
                    + a1.x*h1.x + a1.y*h1.y + a1.z*h1.z + a1.w*h1.w;
            p = wred_sum(p);
            if (lane == 0) lsm[r] = p + Bv[r];
        }
        __syncthreads();
    }

    // ---------- softmax + circular mean -> atan2 ----------
    {
        float lv = (tid < NB) ? lsm[tid] : -INFINITY;
        float m = wred_max(lv);
        if (lane == 0) redA[wid] = m;
        __syncthreads();
        if (tid == 0){
            float mm = -INFINITY;
#pragma unroll
            for (int i = 0; i < NW; ++i) mm = fmaxf(mm, redA[i]);
            stats[0] = mm;
        }
        __syncthreads();
        const float mm = stats[0];
        float es = 0.f, ec = 0.f;
        if (tid < NB){
            float e = expf(lv - mm);
            // bin center: -pi + 2*pi*(k+0.5)/NB
            float center = -3.14159265358979323846f
                         + 6.28318530717958647692f * ((float)tid + 0.5f) * (1.0f/NB);
            es = e * sinf(center);
            ec = e * cosf(center);
        }
        float ss = wred_sum(es);
        float sc = wred_sum(ec);
        if (lane == 0){ redB[wid] = ss; redC[wid] = sc; }
        __syncthreads();
        if (tid == 0){
            float S = 0.f, C = 0.f;
#pragma unroll
            for (int i = 0; i < NW; ++i){ S += redB[i]; C += redC[i]; }
            phi[b] = atan2f(S, C);   // softmax normalizer cancels in atan2
        }
        if (tid < NB) logits[(size_t)b*NB + tid] = lv;
    }
}

extern "C" void kernel_launch(void* const* d_in, const int* in_sizes, int n_in,
                              void* d_out, int out_size, void* d_ws, size_t ws_size,
                              hipStream_t stream)
{
    const float* x   = (const float*)d_in[0];
    const float* lnw = (const float*)d_in[1];
    const float* lnb = (const float*)d_in[2];
    const float* w1  = (const float*)d_in[3];
    const float* b1  = (const float*)d_in[4];
    const float* w2  = (const float*)d_in[5];
    const float* b2  = (const float*)d_in[6];
    const float* w3  = (const float*)d_in[7];
    const float* b3  = (const float*)d_in[8];
    const float* ow  = (const float*)d_in[9];
    const float* ob  = (const float*)d_in[10];

    float* out    = (float*)d_out;
    float* phi    = out;        // [256]
    float* logits = out + BB;   // [256*314]

    pcls_kernel<<<dim3(BB), dim3(NT), 0, stream>>>(
        x, lnw, lnb, w1, b1, w2, b2, w3, b3, ow, ob, phi, logits);
}